// Round 1
// baseline (974.352 us; speedup 1.0000x reference)
//
#include <hip/hip_runtime.h>

// MinGRU stack: 3x (APL z/h + linear recurrence + maxabs-normalize) + APL out.
// B=8, T=2048, Din=D=Dout=64, P=16 knots on [-1,1].

#define WPB 4  // waves (samples) per block in APL kernels

// Computes z = sigmoid(apl(in, vz)) and hbar = apl(in, vh) for each sample.
// One wave per sample; lane = output dim o. Stores interleaved float2(z, hbar).
__global__ __launch_bounds__(256) void apl_dual_kernel(
    const float* __restrict__ in, const float* __restrict__ vz,
    const float* __restrict__ vh, float2* __restrict__ zh, int N)
{
    int lane = threadIdx.x & 63;
    int n = blockIdx.x * WPB + (threadIdx.x >> 6);
    if (n >= N) return;

    float xv = in[(size_t)n * 64 + lane];  // lane l holds input dim l
    float accz = 0.f, acch = 0.f;
#pragma unroll
    for (int i = 0; i < 64; ++i) {
        float xi = __shfl(xv, i, 64);
        float t = (fminf(fmaxf(xi, -1.f), 1.f) + 1.f) * 7.5f;  // [0,15]
        int idx = (int)t;
        idx = idx > 14 ? 14 : idx;
        float fr = t - (float)idx;
        int base = (i * 16 + idx) * 64 + lane;
        float z0 = vz[base], z1 = vz[base + 64];
        float h0 = vh[base], h1 = vh[base + 64];
        accz += z0 + fr * (z1 - z0);
        acch += h0 + fr * (h1 - h0);
    }
    float z = 1.f / (1.f + expf(-accz));
    zh[(size_t)n * 64 + lane] = make_float2(z, acch);
}

// Single-table APL (final output layer).
__global__ __launch_bounds__(256) void apl_out_kernel(
    const float* __restrict__ in, const float* __restrict__ v,
    float* __restrict__ out, int N)
{
    int lane = threadIdx.x & 63;
    int n = blockIdx.x * WPB + (threadIdx.x >> 6);
    if (n >= N) return;

    float xv = in[(size_t)n * 64 + lane];
    float acc = 0.f;
#pragma unroll
    for (int i = 0; i < 64; ++i) {
        float xi = __shfl(xv, i, 64);
        float t = (fminf(fmaxf(xi, -1.f), 1.f) + 1.f) * 7.5f;
        int idx = (int)t;
        idx = idx > 14 ? 14 : idx;
        float fr = t - (float)idx;
        int base = (i * 16 + idx) * 64 + lane;
        float v0 = v[base], v1 = v[base + 64];
        acc += v0 + fr * (v1 - v0);
    }
    out[(size_t)n * 64 + lane] = acc;
}

// h[t] = (1-z)*h[t-1] + z*hbar  (stable form of the reference closed-form),
// then per-row maxabs normalize (all 64 d live in this wave).
// One block per batch element b; thread d = 0..63.
__global__ __launch_bounds__(64) void recur_norm_kernel(
    const float2* __restrict__ zh, float* __restrict__ out, int T)
{
    int b = blockIdx.x;
    int d = threadIdx.x;
    const float2* p = zh + (size_t)b * T * 64 + d;
    float* o = out + (size_t)b * T * 64 + d;

    float h = 0.f;
    for (int t0 = 0; t0 < T; t0 += 8) {
        float2 v[8];
#pragma unroll
        for (int k = 0; k < 8; ++k) v[k] = p[(size_t)(t0 + k) * 64];
        float hs[8];
#pragma unroll
        for (int k = 0; k < 8; ++k) {
            h += v[k].x * (v[k].y - h);
            hs[k] = h;
        }
#pragma unroll
        for (int k = 0; k < 8; ++k) {
            float m = fabsf(hs[k]);
            m = fmaxf(m, __shfl_xor(m, 32, 64));
            m = fmaxf(m, __shfl_xor(m, 16, 64));
            m = fmaxf(m, __shfl_xor(m, 8, 64));
            m = fmaxf(m, __shfl_xor(m, 4, 64));
            m = fmaxf(m, __shfl_xor(m, 2, 64));
            m = fmaxf(m, __shfl_xor(m, 1, 64));
            o[(size_t)(t0 + k) * 64] = hs[k] / (m + 1e-6f);
        }
    }
}

extern "C" void kernel_launch(void* const* d_in, const int* in_sizes, int n_in,
                              void* d_out, int out_size, void* d_ws, size_t ws_size,
                              hipStream_t stream) {
    const float* x    = (const float*)d_in[0];
    const float* vz0  = (const float*)d_in[1];
    const float* vh0  = (const float*)d_in[2];
    const float* vz1  = (const float*)d_in[3];
    const float* vh1  = (const float*)d_in[4];
    const float* vz2  = (const float*)d_in[5];
    const float* vh2  = (const float*)d_in[6];
    const float* vout = (const float*)d_in[7];

    const int N = in_sizes[0] / 64;   // B*T = 16384
    const int T = 2048;
    const int B = N / T;              // 8

    float2* zh = (float2*)d_ws;                                        // 8 MB
    float*  cur = (float*)((char*)d_ws + (size_t)N * 64 * sizeof(float2));  // 4 MB

    dim3 blk(256);
    dim3 grd((N + WPB - 1) / WPB);

    apl_dual_kernel<<<grd, blk, 0, stream>>>(x, vz0, vh0, zh, N);
    recur_norm_kernel<<<B, 64, 0, stream>>>(zh, cur, T);

    apl_dual_kernel<<<grd, blk, 0, stream>>>(cur, vz1, vh1, zh, N);
    recur_norm_kernel<<<B, 64, 0, stream>>>(zh, cur, T);

    apl_dual_kernel<<<grd, blk, 0, stream>>>(cur, vz2, vh2, zh, N);
    recur_norm_kernel<<<B, 64, 0, stream>>>(zh, cur, T);

    apl_out_kernel<<<grd, blk, 0, stream>>>(cur, vout, (float*)d_out, N);
}

// Round 4
// 195.909 us; speedup vs baseline: 4.9735x; 4.9735x over previous
//
#include <hip/hip_runtime.h>

// MinGRU stack: 3x (APL z/h + linear recurrence + maxabs-normalize) + APL out.
// B=8, T=2048, Din=D=Dout=64, P=16 knots on [-1,1].
// Recurrence parallelized as a chunked affine scan (NC chunks of CL steps).

#define WPB 4   // waves (samples) per block in APL kernels
#define NC 64   // chunks per sequence
#define CL 32   // timesteps per chunk (NC*CL == T == 2048)

// ---- table prep: combine (v[p], v[p+1]-v[p]) for z and h into one float4 ----
__global__ __launch_bounds__(256) void prep_dual_kernel(
    const float* __restrict__ vz, const float* __restrict__ vh,
    float4* __restrict__ tab)
{
    int idx = blockIdx.x * blockDim.x + threadIdx.x;   // over 64*15*64
    if (idx >= 64 * 15 * 64) return;
    int o = idx & 63;
    int p = (idx >> 6) % 15;
    int i = idx / (15 * 64);
    int base = (i * 16 + p) * 64 + o;
    float z0 = vz[base], z1 = vz[base + 64];
    float h0 = vh[base], h1 = vh[base + 64];
    tab[idx] = make_float4(z0, z1 - z0, h0, h1 - h0);
}

__global__ __launch_bounds__(256) void prep_out_kernel(
    const float* __restrict__ v, float2* __restrict__ tab)
{
    int idx = blockIdx.x * blockDim.x + threadIdx.x;
    if (idx >= 64 * 15 * 64) return;
    int o = idx & 63;
    int p = (idx >> 6) % 15;
    int i = idx / (15 * 64);
    int base = (i * 16 + p) * 64 + o;
    float v0 = v[base], v1 = v[base + 64];
    tab[idx] = make_float2(v0, v1 - v0);
}

// ---- APL (dual): z = sigmoid(apl_z), hbar = apl_h; one wave per sample ----
__global__ __launch_bounds__(256) void apl_dual_kernel(
    const float* __restrict__ in, const float4* __restrict__ tab,
    float2* __restrict__ zh, int N)
{
    int lane = threadIdx.x & 63;
    int n = blockIdx.x * WPB + (threadIdx.x >> 6);
    if (n >= N) return;

    float xv = in[(size_t)n * 64 + lane];
    float accz = 0.f, acch = 0.f;
#pragma unroll
    for (int i = 0; i < 64; ++i) {
        float xi = __shfl(xv, i, 64);
        float t = (fminf(fmaxf(xi, -1.f), 1.f) + 1.f) * 7.5f;  // [0,15]
        int idx = (int)t;
        idx = idx > 14 ? 14 : idx;
        float fr = t - (float)idx;
        float4 e = tab[(size_t)(i * 15 + idx) * 64 + lane];
        accz += fmaf(fr, e.y, e.x);
        acch += fmaf(fr, e.w, e.z);
    }
    float z = 1.f / (1.f + expf(-accz));
    zh[(size_t)n * 64 + lane] = make_float2(z, acch);
}

// ---- APL (single, output layer) ----
__global__ __launch_bounds__(256) void apl_out_kernel(
    const float* __restrict__ in, const float2* __restrict__ tab,
    float* __restrict__ out, int N)
{
    int lane = threadIdx.x & 63;
    int n = blockIdx.x * WPB + (threadIdx.x >> 6);
    if (n >= N) return;

    float xv = in[(size_t)n * 64 + lane];
    float acc = 0.f;
#pragma unroll
    for (int i = 0; i < 64; ++i) {
        float xi = __shfl(xv, i, 64);
        float t = (fminf(fmaxf(xi, -1.f), 1.f) + 1.f) * 7.5f;
        int idx = (int)t;
        idx = idx > 14 ? 14 : idx;
        float fr = t - (float)idx;
        float2 e = tab[(size_t)(i * 15 + idx) * 64 + lane];
        acc += fmaf(fr, e.y, e.x);
    }
    out[(size_t)n * 64 + lane] = acc;
}

// ---- scan pass 1: per-chunk affine summary (A, B): h_out = A*h_in + B ----
__global__ __launch_bounds__(256) void scan_pass1_kernel(
    const float2* __restrict__ zh, float2* __restrict__ chunkAB, int T)
{
    int lane = threadIdx.x & 63;
    int wid = blockIdx.x * (blockDim.x >> 6) + (threadIdx.x >> 6);  // b*NC + c
    int b = wid / NC, c = wid % NC;
    const float2* p = zh + ((size_t)b * T + (size_t)c * CL) * 64 + lane;

    float A = 1.f, Bc = 0.f;
    for (int k0 = 0; k0 < CL; k0 += 8) {
        float2 v[8];
#pragma unroll
        for (int k = 0; k < 8; ++k) v[k] = p[(size_t)(k0 + k) * 64];
#pragma unroll
        for (int k = 0; k < 8; ++k) {
            float a = 1.f - v[k].x;
            float bb = v[k].x * v[k].y;
            A *= a;
            Bc = fmaf(a, Bc, bb);
        }
    }
    chunkAB[(size_t)wid * 64 + lane] = make_float2(A, Bc);
}

// ---- scan fixup: sequential combine of NC chunk summaries per (b, d) ----
__global__ __launch_bounds__(64) void scan_fixup_kernel(
    const float2* __restrict__ chunkAB, float* __restrict__ hinit)
{
    int b = blockIdx.x;
    int d = threadIdx.x;
    const float2* p = chunkAB + (size_t)b * NC * 64 + d;
    float* o = hinit + (size_t)b * NC * 64 + d;

    float h = 0.f;  // h0 = 0
    for (int c0 = 0; c0 < NC; c0 += 8) {
        float2 ab[8];
#pragma unroll
        for (int k = 0; k < 8; ++k) ab[k] = p[(size_t)(c0 + k) * 64];
#pragma unroll
        for (int k = 0; k < 8; ++k) {
            o[(size_t)(c0 + k) * 64] = h;
            h = fmaf(ab[k].x, h, ab[k].y);
        }
    }
}

// ---- scan pass 2: replay chunk from hinit, fused maxabs-normalize ----
__global__ __launch_bounds__(256) void scan_pass2_kernel(
    const float2* __restrict__ zh, const float* __restrict__ hinit,
    float* __restrict__ out, int T)
{
    int lane = threadIdx.x & 63;
    int wid = blockIdx.x * (blockDim.x >> 6) + (threadIdx.x >> 6);  // b*NC + c
    int b = wid / NC, c = wid % NC;
    const float2* p = zh + ((size_t)b * T + (size_t)c * CL) * 64 + lane;
    float* o = out + ((size_t)b * T + (size_t)c * CL) * 64 + lane;

    float h = hinit[(size_t)wid * 64 + lane];
    for (int k0 = 0; k0 < CL; k0 += 8) {
        float2 v[8];
        float hs[8];
#pragma unroll
        for (int k = 0; k < 8; ++k) v[k] = p[(size_t)(k0 + k) * 64];
#pragma unroll
        for (int k = 0; k < 8; ++k) {
            h = fmaf(v[k].x, v[k].y - h, h);   // h += z*(hbar - h)
            hs[k] = h;
        }
#pragma unroll
        for (int k = 0; k < 8; ++k) {
            float m = fabsf(hs[k]);
            m = fmaxf(m, __shfl_xor(m, 32, 64));
            m = fmaxf(m, __shfl_xor(m, 16, 64));
            m = fmaxf(m, __shfl_xor(m, 8, 64));
            m = fmaxf(m, __shfl_xor(m, 4, 64));
            m = fmaxf(m, __shfl_xor(m, 2, 64));
            m = fmaxf(m, __shfl_xor(m, 1, 64));
            o[(size_t)(k0 + k) * 64] = hs[k] / (m + 1e-6f);
        }
    }
}

extern "C" void kernel_launch(void* const* d_in, const int* in_sizes, int n_in,
                              void* d_out, int out_size, void* d_ws, size_t ws_size,
                              hipStream_t stream) {
    const float* x    = (const float*)d_in[0];
    const float* vz0  = (const float*)d_in[1];
    const float* vh0  = (const float*)d_in[2];
    const float* vz1  = (const float*)d_in[3];
    const float* vh1  = (const float*)d_in[4];
    const float* vz2  = (const float*)d_in[5];
    const float* vh2  = (const float*)d_in[6];
    const float* vout = (const float*)d_in[7];

    const int N = in_sizes[0] / 64;   // B*T = 16384
    const int T = NC * CL;            // 2048
    const int B = N / T;              // 8

    char* ws = (char*)d_ws;
    const size_t TAB_ELEMS = (size_t)64 * 15 * 64;
    float2* zh      = (float2*)ws;                                  // 8 MB
    float*  cur     = (float*)(ws + 8388608);                       // 4 MB
    float4* tab0    = (float4*)(ws + 12582912);                     // 0.94 MB
    float4* tab1    = (float4*)(ws + 13565952);
    float4* tab2    = (float4*)(ws + 14548992);
    float2* tab_out = (float2*)(ws + 15532032);                     // 0.47 MB
    float2* chunkAB = (float2*)(ws + 16023552);                     // 256 KB
    float*  hinit   = (float*)(ws + 16285696);                      // 128 KB

    dim3 pblk(256), pgrd((TAB_ELEMS + 255) / 256);
    prep_dual_kernel<<<pgrd, pblk, 0, stream>>>(vz0, vh0, tab0);
    prep_dual_kernel<<<pgrd, pblk, 0, stream>>>(vz1, vh1, tab1);
    prep_dual_kernel<<<pgrd, pblk, 0, stream>>>(vz2, vh2, tab2);
    prep_out_kernel<<<pgrd, pblk, 0, stream>>>(vout, tab_out);

    dim3 ablk(256), agrd((N + WPB - 1) / WPB);
    dim3 sblk(256), sgrd(B * NC / 4);   // 4 waves (chunks) per block

    const float4* tabs[3] = {tab0, tab1, tab2};
    const float* layer_in = x;
    for (int l = 0; l < 3; ++l) {
        apl_dual_kernel<<<agrd, ablk, 0, stream>>>(layer_in, tabs[l], zh, N);
        scan_pass1_kernel<<<sgrd, sblk, 0, stream>>>(zh, chunkAB, T);
        scan_fixup_kernel<<<B, 64, 0, stream>>>(chunkAB, hinit);
        scan_pass2_kernel<<<sgrd, sblk, 0, stream>>>(zh, hinit, cur, T);
        layer_in = cur;
    }
    apl_out_kernel<<<agrd, ablk, 0, stream>>>(cur, tab_out, (float*)d_out, N);
}